// Round 4
// baseline (150.753 us; speedup 1.0000x reference)
//
#include <hip/hip_runtime.h>
#include <math.h>

// Problem constants
#define Bsz 64
#define IC  512   // in_caps
#define KD  128   // in_dim
#define NC  32    // num_caps
#define DC  32    // dim_caps
#define CHUNK 64  // in_caps per block
#define NCH   8   // IC / CHUNK
#define NBLK  512 // Bsz * NCH
#define NTHR  256

#define CSTR 36   // padded stride for c_sT / wv_sT rows (floats)
#define BSTR 68   // padded stride for bb_s rows
#define WSTR 33   // padded stride for w_s rows: bank=(k+d)%32 -> conflict-free col+row reads

// workspace layout (floats)
#define CXP_SZ (Bsz * NCH * NC * KD)   // 8 MB   cx partials [b][ch][n][k]
#define WV_SZ  (Bsz * NC * KD)         // 1 MB   wv [b][n][k]

// x_s storage: row i holds k-quads rotated by i: quad' = (kq + i) & 31.
// (rotate-by-i, not i>>2: gives even bank spread for BOTH the uv 4-row reads
//  and the cx 8x8-tile reads where 4 adjacent rows sit in different lanes)
__device__ __forceinline__ int xaddr(int i, int kq) {
    return i * KD + ((((kq) + i) & 31) << 2);
}

// ---------------- Kernel A: [uv + bb update] + softmax + cx partials ----------------
// block = (b, ch): b = blk>>3, ch = blk&7 (r0 mapping, stable XCD residency across launches)
__global__ __launch_bounds__(NTHR)
void kA(const float* __restrict__ bb_in, const float* __restrict__ x_g,
        const float* __restrict__ wv_g, float* __restrict__ bb_out,
        float* __restrict__ cxp, int do_uv, int write_bb)
{
    __shared__ float x_s[CHUNK * KD];      // 32 KB, rotated
    __shared__ float bb_s[NC * BSTR];      // 8.5 KB
    __shared__ float scr[KD * CSTR];       // 18 KB union: wv_sT [k][n] then c_sT [i][n]

    const int t = threadIdx.x, blk = blockIdx.x;
    const int b = blk >> 3, ch = blk & 7, i0g = ch * CHUNK;

    // stage x (rotated)
    for (int rep = 0; rep < 8; ++rep) {
        int v = t + rep * NTHR;            // float4 idx 0..2047
        int i = v >> 5, kq = v & 31;
        *(float4*)(x_s + xaddr(i, kq)) =
            *(const float4*)(x_g + ((size_t)(b * IC + i0g + i)) * KD + (kq << 2));
    }
    // stage bb
    for (int rep = 0; rep < 2; ++rep) {
        int v = t + rep * NTHR;            // 0..511
        int n = v >> 4, i4 = v & 15;
        *(float4*)(bb_s + n * BSTR + (i4 << 2)) =
            *(const float4*)(bb_in + ((size_t)(b * NC + n)) * IC + i0g + (i4 << 2));
    }
    if (do_uv) {
        // stage wv transposed: [k][n] with CSTR pad
        for (int rep = 0; rep < 4; ++rep) {
            const int n = t & 31;
            const int k4 = (t >> 5) + (rep << 3);   // 0..31
            float4 v4 = *(const float4*)(wv_g + ((size_t)(b * NC) + n) * KD + (k4 << 2));
            scr[(k4 * 4 + 0) * CSTR + n] = v4.x;
            scr[(k4 * 4 + 1) * CSTR + n] = v4.y;
            scr[(k4 * 4 + 2) * CSTR + n] = v4.z;
            scr[(k4 * 4 + 3) * CSTR + n] = v4.w;
        }
    }
    __syncthreads();

    if (do_uv) {
        // uv = wv @ X^T ; bb += uv   (t<128: 4n x 4i tile each; r0-proven structure)
        if (t < 128) {
            const int tn = t & 7, ti = t >> 3;
            const int n0 = tn << 2, i0 = ti << 2;
            float4 a0 = {0,0,0,0}, a1 = {0,0,0,0}, a2 = {0,0,0,0}, a3 = {0,0,0,0};
            for (int kq = 0; kq < 32; ++kq) {
                const float4 xr0 = *(const float4*)(x_s + xaddr(i0 + 0, kq));
                const float4 xr1 = *(const float4*)(x_s + xaddr(i0 + 1, kq));
                const float4 xr2 = *(const float4*)(x_s + xaddr(i0 + 2, kq));
                const float4 xr3 = *(const float4*)(x_s + xaddr(i0 + 3, kq));
                const float4 w0 = *(const float4*)(scr + (kq * 4 + 0) * CSTR + n0);
                const float4 w1 = *(const float4*)(scr + (kq * 4 + 1) * CSTR + n0);
                const float4 w2 = *(const float4*)(scr + (kq * 4 + 2) * CSTR + n0);
                const float4 w3 = *(const float4*)(scr + (kq * 4 + 3) * CSTR + n0);
                a0.x += xr0.x*w0.x + xr0.y*w1.x + xr0.z*w2.x + xr0.w*w3.x;
                a0.y += xr0.x*w0.y + xr0.y*w1.y + xr0.z*w2.y + xr0.w*w3.y;
                a0.z += xr0.x*w0.z + xr0.y*w1.z + xr0.z*w2.z + xr0.w*w3.z;
                a0.w += xr0.x*w0.w + xr0.y*w1.w + xr0.z*w2.w + xr0.w*w3.w;
                a1.x += xr1.x*w0.x + xr1.y*w1.x + xr1.z*w2.x + xr1.w*w3.x;
                a1.y += xr1.x*w0.y + xr1.y*w1.y + xr1.z*w2.y + xr1.w*w3.y;
                a1.z += xr1.x*w0.z + xr1.y*w1.z + xr1.z*w2.z + xr1.w*w3.z;
                a1.w += xr1.x*w0.w + xr1.y*w1.w + xr1.z*w2.w + xr1.w*w3.w;
                a2.x += xr2.x*w0.x + xr2.y*w1.x + xr2.z*w2.x + xr2.w*w3.x;
                a2.y += xr2.x*w0.y + xr2.y*w1.y + xr2.z*w2.y + xr2.w*w3.y;
                a2.z += xr2.x*w0.z + xr2.y*w1.z + xr2.z*w2.z + xr2.w*w3.z;
                a2.w += xr2.x*w0.w + xr2.y*w1.w + xr2.z*w2.w + xr2.w*w3.w;
                a3.x += xr3.x*w0.x + xr3.y*w1.x + xr3.z*w2.x + xr3.w*w3.x;
                a3.y += xr3.x*w0.y + xr3.y*w1.y + xr3.z*w2.y + xr3.w*w3.y;
                a3.z += xr3.x*w0.z + xr3.y*w1.z + xr3.z*w2.z + xr3.w*w3.z;
                a3.w += xr3.x*w0.w + xr3.y*w1.w + xr3.z*w2.w + xr3.w*w3.w;
            }
            bb_s[(n0+0)*BSTR + i0+0] += a0.x; bb_s[(n0+1)*BSTR + i0+0] += a0.y;
            bb_s[(n0+2)*BSTR + i0+0] += a0.z; bb_s[(n0+3)*BSTR + i0+0] += a0.w;
            bb_s[(n0+0)*BSTR + i0+1] += a1.x; bb_s[(n0+1)*BSTR + i0+1] += a1.y;
            bb_s[(n0+2)*BSTR + i0+1] += a1.z; bb_s[(n0+3)*BSTR + i0+1] += a1.w;
            bb_s[(n0+0)*BSTR + i0+2] += a2.x; bb_s[(n0+1)*BSTR + i0+2] += a2.y;
            bb_s[(n0+2)*BSTR + i0+2] += a2.z; bb_s[(n0+3)*BSTR + i0+2] += a2.w;
            bb_s[(n0+0)*BSTR + i0+3] += a3.x; bb_s[(n0+1)*BSTR + i0+3] += a3.y;
            bb_s[(n0+2)*BSTR + i0+3] += a3.z; bb_s[(n0+3)*BSTR + i0+3] += a3.w;
        }
        __syncthreads();
        if (write_bb) {
            for (int rep = 0; rep < 2; ++rep) {
                int v = t + rep * NTHR;
                int n = v >> 4, i4 = v & 15;
                *(float4*)(bb_out + ((size_t)(b * NC + n)) * IC + i0g + (i4 << 2)) =
                    *(const float4*)(bb_s + n * BSTR + (i4 << 2));
            }
        }
    }

    // softmax over n for each ii; ALL 256 threads: 4 threads per row ii, 8 n's each,
    // quad reduction via shfl_xor(1,2). Write c^T into scr.
    {
        const int ii = t >> 2, part = t & 3;
        float e8[8];
        float m = -1e30f;
        #pragma unroll
        for (int j = 0; j < 8; ++j) {
            e8[j] = bb_s[(part * 8 + j) * BSTR + ii];
            m = fmaxf(m, e8[j]);
        }
        m = fmaxf(m, __shfl_xor(m, 1, 64));
        m = fmaxf(m, __shfl_xor(m, 2, 64));
        float sum = 0.f;
        #pragma unroll
        for (int j = 0; j < 8; ++j) { e8[j] = __expf(e8[j] - m); sum += e8[j]; }
        sum += __shfl_xor(sum, 1, 64);
        sum += __shfl_xor(sum, 2, 64);
        const float inv = 1.f / sum;
        float* crow = scr + ii * CSTR + part * 8;
        #pragma unroll
        for (int j = 0; j < 8; ++j) crow[j] = e8[j] * inv;
    }
    __syncthreads();

    // cx = C @ X: 8n x 8k tiles, i-split 4 in-lane (isp = t&3), butterfly combine.
    // Per thread: 16 ii iterations, 4 ds_read_b128 each (2 c + 2 x) for 64 MAC
    // -> half the LDS instruction count of the old 4x4 tiling.
    {
        const int isp = t & 3, ko = (t >> 2) & 15, no = t >> 6;
        const int n0 = no << 3, kq0 = ko << 1;
        float4 accA[8], accB[8];           // rows 0..7: cols k0..k0+3 (A), k0+4..k0+7 (B)
        #pragma unroll
        for (int r = 0; r < 8; ++r) { accA[r] = (float4){0,0,0,0}; accB[r] = (float4){0,0,0,0}; }
        for (int j = 0; j < 16; ++j) {
            const int ii = (j << 2) + isp;
            const float4 cA = *(const float4*)(scr + ii * CSTR + n0);
            const float4 cB = *(const float4*)(scr + ii * CSTR + n0 + 4);
            const float4 xA = *(const float4*)(x_s + xaddr(ii, kq0));
            const float4 xB = *(const float4*)(x_s + xaddr(ii, kq0 + 1));
            const float c0 = cA.x, c1 = cA.y, c2 = cA.z, c3 = cA.w;
            const float c4 = cB.x, c5 = cB.y, c6 = cB.z, c7 = cB.w;
            accA[0].x += c0*xA.x; accA[0].y += c0*xA.y; accA[0].z += c0*xA.z; accA[0].w += c0*xA.w;
            accB[0].x += c0*xB.x; accB[0].y += c0*xB.y; accB[0].z += c0*xB.z; accB[0].w += c0*xB.w;
            accA[1].x += c1*xA.x; accA[1].y += c1*xA.y; accA[1].z += c1*xA.z; accA[1].w += c1*xA.w;
            accB[1].x += c1*xB.x; accB[1].y += c1*xB.y; accB[1].z += c1*xB.z; accB[1].w += c1*xB.w;
            accA[2].x += c2*xA.x; accA[2].y += c2*xA.y; accA[2].z += c2*xA.z; accA[2].w += c2*xA.w;
            accB[2].x += c2*xB.x; accB[2].y += c2*xB.y; accB[2].z += c2*xB.z; accB[2].w += c2*xB.w;
            accA[3].x += c3*xA.x; accA[3].y += c3*xA.y; accA[3].z += c3*xA.z; accA[3].w += c3*xA.w;
            accB[3].x += c3*xB.x; accB[3].y += c3*xB.y; accB[3].z += c3*xB.z; accB[3].w += c3*xB.w;
            accA[4].x += c4*xA.x; accA[4].y += c4*xA.y; accA[4].z += c4*xA.z; accA[4].w += c4*xA.w;
            accB[4].x += c4*xB.x; accB[4].y += c4*xB.y; accB[4].z += c4*xB.z; accB[4].w += c4*xB.w;
            accA[5].x += c5*xA.x; accA[5].y += c5*xA.y; accA[5].z += c5*xA.z; accA[5].w += c5*xA.w;
            accB[5].x += c5*xB.x; accB[5].y += c5*xB.y; accB[5].z += c5*xB.z; accB[5].w += c5*xB.w;
            accA[6].x += c6*xA.x; accA[6].y += c6*xA.y; accA[6].z += c6*xA.z; accA[6].w += c6*xA.w;
            accB[6].x += c6*xB.x; accB[6].y += c6*xB.y; accB[6].z += c6*xB.z; accB[6].w += c6*xB.w;
            accA[7].x += c7*xA.x; accA[7].y += c7*xA.y; accA[7].z += c7*xA.z; accA[7].w += c7*xA.w;
            accB[7].x += c7*xB.x; accB[7].y += c7*xB.y; accB[7].z += c7*xB.z; accB[7].w += c7*xB.w;
        }
        // butterfly over isp (lane bits 0-1): every lane ends with the full i-sum
        #pragma unroll
        for (int r = 0; r < 8; ++r) {
            accA[r].x += __shfl_xor(accA[r].x, 1, 64); accA[r].x += __shfl_xor(accA[r].x, 2, 64);
            accA[r].y += __shfl_xor(accA[r].y, 1, 64); accA[r].y += __shfl_xor(accA[r].y, 2, 64);
            accA[r].z += __shfl_xor(accA[r].z, 1, 64); accA[r].z += __shfl_xor(accA[r].z, 2, 64);
            accA[r].w += __shfl_xor(accA[r].w, 1, 64); accA[r].w += __shfl_xor(accA[r].w, 2, 64);
            accB[r].x += __shfl_xor(accB[r].x, 1, 64); accB[r].x += __shfl_xor(accB[r].x, 2, 64);
            accB[r].y += __shfl_xor(accB[r].y, 1, 64); accB[r].y += __shfl_xor(accB[r].y, 2, 64);
            accB[r].z += __shfl_xor(accB[r].z, 1, 64); accB[r].z += __shfl_xor(accB[r].z, 2, 64);
            accB[r].w += __shfl_xor(accB[r].w, 1, 64); accB[r].w += __shfl_xor(accB[r].w, 2, 64);
        }
        // lane (isp) writes rows isp and isp+4 of its 8x8 tile
        float* base = cxp + ((size_t)(b * NCH + ch)) * NC * KD + (ko << 3);
        {
            const int r0 = isp, r1 = isp + 4;
            float* p0 = base + (size_t)(n0 + r0) * KD;
            float* p1 = base + (size_t)(n0 + r1) * KD;
            *(float4*)(p0)     = accA[r0];
            *(float4*)(p0 + 4) = accB[r0];
            *(float4*)(p1)     = accA[r1];
            *(float4*)(p1 + 4) = accB[r1];
        }
    }
}

// ---------------- Kernel B: reduce partials, s = cx@W[n], squash, wv or out ----------------
// (unchanged from round 3 — verified neutral-or-better)
__global__ __launch_bounds__(NTHR)
void kB(const float* __restrict__ cxp, const float* __restrict__ W_g,
        float* __restrict__ wv_g, float* __restrict__ out_g, int final_)
{
    __shared__ float w_s[KD * WSTR];       // 16.5 KB, padded [k][d], bank=(k+d)%32
    __shared__ float cxs[4 * KD];          // 2 KB: per-wave reduced cx row
    __shared__ float vb[4 * DC];           // 512 B: per-wave squashed v

    const int t = threadIdx.x, blk = blockIdx.x;
    const int pb_n = blk & 31, pb_b0 = (blk >> 5) * 4;
    const int w = t >> 6, l = t & 63;
    const int b = pb_b0 + w;

    for (int rep = 0; rep < 4; ++rep) {
        int v = t + rep * NTHR;            // 0..1023 float4s
        int k = v >> 3, d0 = (v & 7) << 2;
        float4 w4 = *(const float4*)(W_g + (size_t)pb_n * KD * DC + ((size_t)v << 2));
        float* dst = w_s + k * WSTR + d0;
        dst[0] = w4.x; dst[1] = w4.y; dst[2] = w4.z; dst[3] = w4.w;
    }
    {
        float c0 = 0.f, c1 = 0.f;
        const float* p = cxp + ((size_t)b * NCH * NC + pb_n) * KD;
        #pragma unroll
        for (int c2 = 0; c2 < NCH; ++c2) {
            c0 += p[(size_t)c2 * NC * KD + l];
            c1 += p[(size_t)c2 * NC * KD + l + 64];
        }
        cxs[w * KD + l] = c0; cxs[w * KD + l + 64] = c1;
    }
    __syncthreads();

    const int dgrp = l & 7, d0 = dgrp << 2, kg = l >> 3;
    const float* cxw = cxs + w * KD;
    float4 acc = {0,0,0,0};
    #pragma unroll
    for (int j = 0; j < 16; ++j) {
        const int k = (j << 3) + kg;
        const float* wr = w_s + k * WSTR + d0;
        const float cv = cxw[k];
        acc.x += cv * wr[0]; acc.y += cv * wr[1]; acc.z += cv * wr[2]; acc.w += cv * wr[3];
    }
    #pragma unroll
    for (int off = 8; off < 64; off <<= 1) {
        acc.x += __shfl_xor(acc.x, off, 64);
        acc.y += __shfl_xor(acc.y, off, 64);
        acc.z += __shfl_xor(acc.z, off, 64);
        acc.w += __shfl_xor(acc.w, off, 64);
    }
    float ss = acc.x*acc.x + acc.y*acc.y + acc.z*acc.z + acc.w*acc.w;
    #pragma unroll
    for (int off = 1; off < 8; off <<= 1) ss += __shfl_xor(ss, off, 64);
    const float scale = ss / ((1.f + ss) * (sqrtf(ss) + 1e-8f));
    float4 v4; v4.x = acc.x*scale; v4.y = acc.y*scale; v4.z = acc.z*scale; v4.w = acc.w*scale;

    if (final_) {
        if (kg == 0) *(float4*)(out_g + ((size_t)(b * NC) + pb_n) * DC + d0) = v4;
    } else {
        float* vbw = vb + w * DC;
        if (kg == 0) *(float4*)(vbw + d0) = v4;
        __syncthreads();
        float wv0 = 0.f, wv1 = 0.f;
        #pragma unroll
        for (int j = 0; j < 8; ++j) {
            const float4 vv = *(const float4*)(vbw + (j << 2));
            const float* wa = w_s + l * WSTR + (j << 2);
            const float* wb = w_s + (l + 64) * WSTR + (j << 2);
            wv0 += wa[0]*vv.x + wa[1]*vv.y + wa[2]*vv.z + wa[3]*vv.w;
            wv1 += wb[0]*vv.x + wb[1]*vv.y + wb[2]*vv.z + wb[3]*vv.w;
        }
        float* wrow = wv_g + ((size_t)(b * NC) + pb_n) * KD;
        wrow[l] = wv0; wrow[l + 64] = wv1;
    }
}

extern "C" void kernel_launch(void* const* d_in, const int* in_sizes, int n_in,
                              void* d_out, int out_size, void* d_ws, size_t ws_size,
                              hipStream_t stream) {
    const float* x  = (const float*)d_in[0];
    const float* W  = (const float*)d_in[1];
    const float* b0 = (const float*)d_in[2];
    float* out = (float*)d_out;

    float* cxp   = (float*)d_ws;                 // 8 MB
    float* wv    = cxp + CXP_SZ;                 // 1 MB
    float* bb_ws = wv + WV_SZ;                   // 4 MB

    // iter 0: softmax(b0) + cx
    kA<<<NBLK, NTHR, 0, stream>>>(b0, x, nullptr, nullptr, cxp, 0, 0);
    kB<<<NBLK, NTHR, 0, stream>>>(cxp, W, wv, nullptr, 0);
    // iter 1: uv+bb (persist) + softmax + cx
    kA<<<NBLK, NTHR, 0, stream>>>(b0, x, wv, bb_ws, cxp, 1, 1);
    kB<<<NBLK, NTHR, 0, stream>>>(cxp, W, wv, nullptr, 0);
    // iter 2: uv+bb + softmax + cx (bb not persisted)
    kA<<<NBLK, NTHR, 0, stream>>>(bb_ws, x, wv, nullptr, cxp, 1, 0);
    kB<<<NBLK, NTHR, 0, stream>>>(cxp, W, nullptr, out, 1);
}

// Round 5
// 129.498 us; speedup vs baseline: 1.1641x; 1.1641x over previous
//
#include <hip/hip_runtime.h>
#include <math.h>

// Problem constants
#define Bsz 64
#define IC  512   // in_caps
#define KD  128   // in_dim
#define NC  32    // num_caps
#define DC  32    // dim_caps
#define CHUNK 32  // in_caps per block (halved vs r3: 4 blocks/CU instead of 2)
#define NCH   16  // IC / CHUNK
#define NBLK  1024 // Bsz * NCH
#define NTHR  256
#define KBBLK 512 // kB grid: (Bsz/4) * NC

#define CSTR 36   // padded stride for c_sT / wv_sT rows (floats)
#define BSTR 36   // padded stride for bb_s rows (CHUNK=32 + pad 4)
#define WSTR 33   // padded stride for w_s rows: bank=(k+d)%32 -> conflict-free col+row reads

// workspace layout (floats)
#define CXP_SZ (Bsz * NCH * NC * KD)   // 16 MB  cx partials [b][ch][n][k]
#define WV_SZ  (Bsz * NC * KD)         // 1 MB   wv [b][n][k]

// x_s storage: row i holds k-quads rotated by (i>>2): quad' = (quad + (i>>2)) & 31
__device__ __forceinline__ int xaddr(int i, int kq) {
    return i * KD + ((((kq) + (i >> 2)) & 31) << 2);
}

// ---------------- Kernel A: [uv + bb update] + softmax + cx partials ----------------
// block = (b, ch): b = blk>>4, ch = blk&15. LDS 38.5 KB -> 4 blocks/CU, 16 waves/CU.
__global__ __launch_bounds__(NTHR)
void kA(const float* __restrict__ bb_in, const float* __restrict__ x_g,
        const float* __restrict__ wv_g, float* __restrict__ bb_out,
        float* __restrict__ cxp, int do_uv, int write_bb)
{
    __shared__ float x_s[CHUNK * KD];      // 16 KB, quad-rotated
    __shared__ float bb_s[NC * BSTR];      // 4.5 KB
    __shared__ float scr[KD * CSTR];       // 18 KB union: wv_sT [k][n] then c_sT [i][n]

    const int t = threadIdx.x, blk = blockIdx.x;
    const int b = blk >> 4, ch = blk & 15, i0g = ch * CHUNK;

    // stage x (rotated): 1024 float4s
    for (int rep = 0; rep < 4; ++rep) {
        int v = t + rep * NTHR;            // float4 idx 0..1023
        int i = v >> 5, kq = v & 31;
        *(float4*)(x_s + xaddr(i, kq)) =
            *(const float4*)(x_g + ((size_t)(b * IC + i0g + i)) * KD + (kq << 2));
    }
    // stage bb: 256 float4s (32 rows x 8)
    {
        int n = t >> 3, i4 = t & 7;
        *(float4*)(bb_s + n * BSTR + (i4 << 2)) =
            *(const float4*)(bb_in + ((size_t)(b * NC + n)) * IC + i0g + (i4 << 2));
    }
    if (do_uv) {
        // stage wv transposed: [k][n] with CSTR pad (independent of CHUNK)
        for (int rep = 0; rep < 4; ++rep) {
            const int n = t & 31;
            const int k4 = (t >> 5) + (rep << 3);   // 0..31
            float4 v4 = *(const float4*)(wv_g + ((size_t)(b * NC) + n) * KD + (k4 << 2));
            scr[(k4 * 4 + 0) * CSTR + n] = v4.x;
            scr[(k4 * 4 + 1) * CSTR + n] = v4.y;
            scr[(k4 * 4 + 2) * CSTR + n] = v4.z;
            scr[(k4 * 4 + 3) * CSTR + n] = v4.w;
        }
    }
    __syncthreads();

    if (do_uv) {
        // uv = wv @ X^T ; bb += uv   (t<64: 4n x 4i tile each; same 8-read/64-MAC
        // shape as the r0/r3-proven loop, i range is 0..31 so 8x8=64 tiles)
        if (t < 64) {
            const int tn = t & 7, ti = t >> 3;      // ti 0..7
            const int n0 = tn << 2, i0 = ti << 2;
            float4 a0 = {0,0,0,0}, a1 = {0,0,0,0}, a2 = {0,0,0,0}, a3 = {0,0,0,0};
            for (int kq = 0; kq < 32; ++kq) {
                const float4 xr0 = *(const float4*)(x_s + xaddr(i0 + 0, kq));
                const float4 xr1 = *(const float4*)(x_s + xaddr(i0 + 1, kq));
                const float4 xr2 = *(const float4*)(x_s + xaddr(i0 + 2, kq));
                const float4 xr3 = *(const float4*)(x_s + xaddr(i0 + 3, kq));
                const float4 w0 = *(const float4*)(scr + (kq * 4 + 0) * CSTR + n0);
                const float4 w1 = *(const float4*)(scr + (kq * 4 + 1) * CSTR + n0);
                const float4 w2 = *(const float4*)(scr + (kq * 4 + 2) * CSTR + n0);
                const float4 w3 = *(const float4*)(scr + (kq * 4 + 3) * CSTR + n0);
                a0.x += xr0.x*w0.x + xr0.y*w1.x + xr0.z*w2.x + xr0.w*w3.x;
                a0.y += xr0.x*w0.y + xr0.y*w1.y + xr0.z*w2.y + xr0.w*w3.y;
                a0.z += xr0.x*w0.z + xr0.y*w1.z + xr0.z*w2.z + xr0.w*w3.z;
                a0.w += xr0.x*w0.w + xr0.y*w1.w + xr0.z*w2.w + xr0.w*w3.w;
                a1.x += xr1.x*w0.x + xr1.y*w1.x + xr1.z*w2.x + xr1.w*w3.x;
                a1.y += xr1.x*w0.y + xr1.y*w1.y + xr1.z*w2.y + xr1.w*w3.y;
                a1.z += xr1.x*w0.z + xr1.y*w1.z + xr1.z*w2.z + xr1.w*w3.z;
                a1.w += xr1.x*w0.w + xr1.y*w1.w + xr1.z*w2.w + xr1.w*w3.w;
                a2.x += xr2.x*w0.x + xr2.y*w1.x + xr2.z*w2.x + xr2.w*w3.x;
                a2.y += xr2.x*w0.y + xr2.y*w1.y + xr2.z*w2.y + xr2.w*w3.y;
                a2.z += xr2.x*w0.z + xr2.y*w1.z + xr2.z*w2.z + xr2.w*w3.z;
                a2.w += xr2.x*w0.w + xr2.y*w1.w + xr2.z*w2.w + xr2.w*w3.w;
                a3.x += xr3.x*w0.x + xr3.y*w1.x + xr3.z*w2.x + xr3.w*w3.x;
                a3.y += xr3.x*w0.y + xr3.y*w1.y + xr3.z*w2.y + xr3.w*w3.y;
                a3.z += xr3.x*w0.z + xr3.y*w1.z + xr3.z*w2.z + xr3.w*w3.z;
                a3.w += xr3.x*w0.w + xr3.y*w1.w + xr3.z*w2.w + xr3.w*w3.w;
            }
            bb_s[(n0+0)*BSTR + i0+0] += a0.x; bb_s[(n0+1)*BSTR + i0+0] += a0.y;
            bb_s[(n0+2)*BSTR + i0+0] += a0.z; bb_s[(n0+3)*BSTR + i0+0] += a0.w;
            bb_s[(n0+0)*BSTR + i0+1] += a1.x; bb_s[(n0+1)*BSTR + i0+1] += a1.y;
            bb_s[(n0+2)*BSTR + i0+1] += a1.z; bb_s[(n0+3)*BSTR + i0+1] += a1.w;
            bb_s[(n0+0)*BSTR + i0+2] += a2.x; bb_s[(n0+1)*BSTR + i0+2] += a2.y;
            bb_s[(n0+2)*BSTR + i0+2] += a2.z; bb_s[(n0+3)*BSTR + i0+2] += a2.w;
            bb_s[(n0+0)*BSTR + i0+3] += a3.x; bb_s[(n0+1)*BSTR + i0+3] += a3.y;
            bb_s[(n0+2)*BSTR + i0+3] += a3.z; bb_s[(n0+3)*BSTR + i0+3] += a3.w;
        }
        __syncthreads();
        if (write_bb) {
            int n = t >> 3, i4 = t & 7;
            *(float4*)(bb_out + ((size_t)(b * NC + n)) * IC + i0g + (i4 << 2)) =
                *(const float4*)(bb_s + n * BSTR + (i4 << 2));
        }
    }

    // softmax over n for each ii (t<32, serial over 32 n; r3-proven form)
    if (t < CHUNK) {
        const int ii = t;
        float m = -1e30f;
        #pragma unroll
        for (int n = 0; n < NC; ++n) m = fmaxf(m, bb_s[n * BSTR + ii]);
        float e[NC]; float sum = 0.f;
        #pragma unroll
        for (int n = 0; n < NC; ++n) { float ev = __expf(bb_s[n * BSTR + ii] - m); e[n] = ev; sum += ev; }
        const float inv = 1.f / sum;
        float* crow = scr + ii * CSTR;
        #pragma unroll
        for (int n = 0; n < NC; ++n) crow[n] = e[n] * inv;
    }
    __syncthreads();

    // cx = C @ X (32n x 128k over 32 i); each thread 4n x 4k (r3-proven form)
    {
        const int tn = t & 7, tk = t >> 3;
        const int n0 = tn << 2;
        float4 acc0 = {0,0,0,0}, acc1 = {0,0,0,0}, acc2 = {0,0,0,0}, acc3 = {0,0,0,0};
        for (int ii = 0; ii < CHUNK; ++ii) {
            const float4 c4 = *(const float4*)(scr + ii * CSTR + n0);
            const float4 x4 = *(const float4*)(x_s + xaddr(ii, tk));
            acc0.x += c4.x*x4.x; acc0.y += c4.x*x4.y; acc0.z += c4.x*x4.z; acc0.w += c4.x*x4.w;
            acc1.x += c4.y*x4.x; acc1.y += c4.y*x4.y; acc1.z += c4.y*x4.z; acc1.w += c4.y*x4.w;
            acc2.x += c4.z*x4.x; acc2.y += c4.z*x4.y; acc2.z += c4.z*x4.z; acc2.w += c4.z*x4.w;
            acc3.x += c4.w*x4.x; acc3.y += c4.w*x4.y; acc3.z += c4.w*x4.z; acc3.w += c4.w*x4.w;
        }
        float* base = cxp + ((size_t)(b * NCH + ch)) * NC * KD + (tk << 2);
        *(float4*)(base + (size_t)(n0 + 0) * KD) = acc0;
        *(float4*)(base + (size_t)(n0 + 1) * KD) = acc1;
        *(float4*)(base + (size_t)(n0 + 2) * KD) = acc2;
        *(float4*)(base + (size_t)(n0 + 3) * KD) = acc3;
    }
}

// ---------------- Kernel B: reduce partials, s = cx@W[n], squash, wv or out ----------------
// (r3 structure, verified; only the partial-reduce loop widens to NCH=16)
__global__ __launch_bounds__(NTHR)
void kB(const float* __restrict__ cxp, const float* __restrict__ W_g,
        float* __restrict__ wv_g, float* __restrict__ out_g, int final_)
{
    __shared__ float w_s[KD * WSTR];       // 16.5 KB, padded [k][d], bank=(k+d)%32
    __shared__ float cxs[4 * KD];          // 2 KB: per-wave reduced cx row
    __shared__ float vb[4 * DC];           // 512 B: per-wave squashed v

    const int t = threadIdx.x, blk = blockIdx.x;
    const int pb_n = blk & 31, pb_b0 = (blk >> 5) * 4;
    const int w = t >> 6, l = t & 63;
    const int b = pb_b0 + w;

    for (int rep = 0; rep < 4; ++rep) {
        int v = t + rep * NTHR;            // 0..1023 float4s
        int k = v >> 3, d0 = (v & 7) << 2;
        float4 w4 = *(const float4*)(W_g + (size_t)pb_n * KD * DC + ((size_t)v << 2));
        float* dst = w_s + k * WSTR + d0;
        dst[0] = w4.x; dst[1] = w4.y; dst[2] = w4.z; dst[3] = w4.w;
    }
    {
        float c0 = 0.f, c1 = 0.f;
        const float* p = cxp + ((size_t)b * NCH * NC + pb_n) * KD;
        #pragma unroll
        for (int c2 = 0; c2 < NCH; ++c2) {
            c0 += p[(size_t)c2 * NC * KD + l];
            c1 += p[(size_t)c2 * NC * KD + l + 64];
        }
        cxs[w * KD + l] = c0; cxs[w * KD + l + 64] = c1;
    }
    __syncthreads();

    const int dgrp = l & 7, d0 = dgrp << 2, kg = l >> 3;
    const float* cxw = cxs + w * KD;
    float4 acc = {0,0,0,0};
    #pragma unroll
    for (int j = 0; j < 16; ++j) {
        const int k = (j << 3) + kg;
        const float* wr = w_s + k * WSTR + d0;
        const float cv = cxw[k];
        acc.x += cv * wr[0]; acc.y += cv * wr[1]; acc.z += cv * wr[2]; acc.w += cv * wr[3];
    }
    #pragma unroll
    for (int off = 8; off < 64; off <<= 1) {
        acc.x += __shfl_xor(acc.x, off, 64);
        acc.y += __shfl_xor(acc.y, off, 64);
        acc.z += __shfl_xor(acc.z, off, 64);
        acc.w += __shfl_xor(acc.w, off, 64);
    }
    float ss = acc.x*acc.x + acc.y*acc.y + acc.z*acc.z + acc.w*acc.w;
    #pragma unroll
    for (int off = 1; off < 8; off <<= 1) ss += __shfl_xor(ss, off, 64);
    const float scale = ss / ((1.f + ss) * (sqrtf(ss) + 1e-8f));
    float4 v4; v4.x = acc.x*scale; v4.y = acc.y*scale; v4.z = acc.z*scale; v4.w = acc.w*scale;

    if (final_) {
        if (kg == 0) *(float4*)(out_g + ((size_t)(b * NC) + pb_n) * DC + d0) = v4;
    } else {
        float* vbw = vb + w * DC;
        if (kg == 0) *(float4*)(vbw + d0) = v4;
        __syncthreads();
        float wv0 = 0.f, wv1 = 0.f;
        #pragma unroll
        for (int j = 0; j < 8; ++j) {
            const float4 vv = *(const float4*)(vbw + (j << 2));
            const float* wa = w_s + l * WSTR + (j << 2);
            const float* wb = w_s + (l + 64) * WSTR + (j << 2);
            wv0 += wa[0]*vv.x + wa[1]*vv.y + wa[2]*vv.z + wa[3]*vv.w;
            wv1 += wb[0]*vv.x + wb[1]*vv.y + wb[2]*vv.z + wb[3]*vv.w;
        }
        float* wrow = wv_g + ((size_t)(b * NC) + pb_n) * KD;
        wrow[l] = wv0; wrow[l + 64] = wv1;
    }
}

extern "C" void kernel_launch(void* const* d_in, const int* in_sizes, int n_in,
                              void* d_out, int out_size, void* d_ws, size_t ws_size,
                              hipStream_t stream) {
    const float* x  = (const float*)d_in[0];
    const float* W  = (const float*)d_in[1];
    const float* b0 = (const float*)d_in[2];
    float* out = (float*)d_out;

    float* cxp   = (float*)d_ws;                 // 16 MB
    float* wv    = cxp + CXP_SZ;                 // 1 MB
    float* bb_ws = wv + WV_SZ;                   // 4 MB

    // iter 0: softmax(b0) + cx
    kA<<<NBLK, NTHR, 0, stream>>>(b0, x, nullptr, nullptr, cxp, 0, 0);
    kB<<<KBBLK, NTHR, 0, stream>>>(cxp, W, wv, nullptr, 0);
    // iter 1: uv+bb (persist) + softmax + cx
    kA<<<NBLK, NTHR, 0, stream>>>(b0, x, wv, bb_ws, cxp, 1, 1);
    kB<<<KBBLK, NTHR, 0, stream>>>(cxp, W, wv, nullptr, 0);
    // iter 2: uv+bb + softmax + cx (bb not persisted)
    kA<<<NBLK, NTHR, 0, stream>>>(bb_ws, x, wv, nullptr, cxp, 1, 0);
    kB<<<KBBLK, NTHR, 0, stream>>>(cxp, W, nullptr, out, 1);
}